// Round 13
// baseline (22390.305 us; speedup 1.0000x reference)
//
#include <hip/hip_runtime.h>
#include <hip/hip_bf16.h>
#include <cstdint>

#define TB 16
#define TT 16384
#define TI 64
#define TH 128
#define TG 512  // 4*H

typedef _Float16 f16x8 __attribute__((ext_vector_type(8)));
typedef float    f32x4 __attribute__((ext_vector_type(4)));

typedef const float __attribute__((address_space(1)))* gcfp;
typedef float __attribute__((address_space(1)))*       gfp;

__device__ __forceinline__ float sigf(float z) {
    return 1.0f / (1.0f + __expf(-z));
}
__device__ __forceinline__ float tanhf_fast(float z) {
    return 2.0f / (1.0f + __expf(-2.0f * z)) - 1.0f;
}
__device__ __forceinline__ float4 ld4(const float* p) {
    return *reinterpret_cast<const float4*>(p);
}
__device__ __forceinline__ void fma4(float4& acc, const float4 w, const float4 h) {
    acc.x = fmaf(w.x, h.x, acc.x);
    acc.y = fmaf(w.y, h.y, acc.y);
    acc.z = fmaf(w.z, h.z, acc.z);
    acc.w = fmaf(w.w, h.w, acc.w);
}
__device__ __forceinline__ float hsum4(const float4 a) {
    return (a.x + a.y) + (a.z + a.w);
}
__device__ __forceinline__ void pin_agpr(f16x8& v) {
    asm volatile("" : "+a"(v));
}

// ---------------------------------------------------------------------------
// gx = x @ W_ih^T + b_ih + b_hh
// ---------------------------------------------------------------------------
__global__ __launch_bounds__(256, 2) void gx_precompute(
    const float* __restrict__ x, const float* __restrict__ W_ih,
    const float* __restrict__ b_ih, const float* __restrict__ b_hh,
    float* __restrict__ gx)
{
    const int tid  = threadIdx.x;
    const int j    = tid & (TH - 1);
    const int pair = tid >> 7;
    const int row_a = pair * 2 * TH + j;
    const int row_b = row_a + TH;

    float4 ua[TI / 4], ub[TI / 4];
#pragma unroll
    for (int k4 = 0; k4 < TI / 4; ++k4) {
        ua[k4] = ld4(W_ih + (size_t)row_a * TI + k4 * 4);
        ub[k4] = ld4(W_ih + (size_t)row_b * TI + k4 * 4);
    }
    const float bias_a = b_ih[row_a] + b_hh[row_a];
    const float bias_b = b_ih[row_b] + b_hh[row_b];

    __shared__ __align__(16) float xs[2][TI];
    const int ROWS = 128;
    const size_t r0 = (size_t)blockIdx.x * ROWS;

    if (tid < TI / 4)
        *reinterpret_cast<float4*>(&xs[0][tid * 4]) = ld4(x + r0 * TI + tid * 4);
    __syncthreads();
    float4 xreg = make_float4(0.f, 0.f, 0.f, 0.f);
    if (tid < TI / 4) xreg = ld4(x + (r0 + 1) * TI + tid * 4);

#pragma unroll 1
    for (int rr = 0; rr < ROWS; ++rr) {
        const float* xrow = xs[rr & 1];
        float4 aa = make_float4(0.f, 0.f, 0.f, 0.f);
        float4 ab = make_float4(0.f, 0.f, 0.f, 0.f);
#pragma unroll
        for (int k4 = 0; k4 < TI / 4; ++k4) {
            const float4 x4 = *reinterpret_cast<const float4*>(&xrow[k4 * 4]);
            fma4(aa, ua[k4], x4);
            fma4(ab, ub[k4], x4);
        }
        if (tid < TI / 4) {
            if (rr + 1 < ROWS)
                *reinterpret_cast<float4*>(&xs[(rr + 1) & 1][tid * 4]) = xreg;
            if (rr + 2 < ROWS) xreg = ld4(x + (r0 + rr + 2) * TI + tid * 4);
        }
        float* grow = gx + (r0 + rr) * (size_t)TG;
        grow[row_a] = hsum4(aa) + bias_a;
        grow[row_b] = hsum4(ab) + bias_b;

        asm volatile("s_waitcnt lgkmcnt(0)" ::: "memory");
        __builtin_amdgcn_s_barrier();
    }
}

// ---------------------------------------------------------------------------
// MFMA LSTM scan, 4-wave version (R11 ablation: per-SIMD issue stream, not
// gx loads or barriers, dominates). 256 threads = 4 waves = 1 wave/SIMD.
// Wave w owns channels [32w, 32w+32): per gate s, N-tiles 8s+2w and 8s+2w+1.
// 32 MFMA/wave/step, chains split 2-deep + VALU add. Lane (c,oct):
// uu=oct&1 selects which 16-channel half this lane updates (oct 2,3 dup).
// h f16 double-buffered in LDS, ONE barrier/step. gx: 4-slot register ring.
// ---------------------------------------------------------------------------
__global__
__attribute__((amdgpu_flat_work_group_size(256, 256), amdgpu_waves_per_eu(1, 1)))
void lstm_scan_mfma4(
    const float* __restrict__ W_hh, const float* __restrict__ gx,
    float* __restrict__ y, float* __restrict__ hn, float* __restrict__ cn)
{
    const int b    = blockIdx.x;
    const int tid  = threadIdx.x;
    const int w    = tid >> 6;        // wave 0..3
    const int lane = tid & 63;
    const int c    = lane & 15;       // N col within tile
    const int oct  = lane >> 4;       // K octet selector
    const int uu   = oct & 1;         // which 16-channel half this lane updates
    const int ch   = 32 * w + 16 * uu + c;   // channel this lane owns

    __shared__ __align__(16) _Float16 h_lds[2][TH];

    // B fragments: bf[s][u][kt] = W_hh[row=128s+32w+16u+c][col=32kt+8oct ..+7]
    f16x8 bf[4][2][4];
#pragma unroll
    for (int s = 0; s < 4; ++s) {
#pragma unroll
        for (int u = 0; u < 2; ++u) {
#pragma unroll
            for (int kt = 0; kt < 4; ++kt) {
                const float* wr = W_hh +
                    (size_t)(s * TH + 32 * w + 16 * u + c) * TH + kt * 32 + oct * 8;
                const float4 lo = ld4(wr);
                const float4 hi = ld4(wr + 4);
                bf[s][u][kt] = f16x8{(_Float16)lo.x, (_Float16)lo.y,
                                     (_Float16)lo.z, (_Float16)lo.w,
                                     (_Float16)hi.x, (_Float16)hi.y,
                                     (_Float16)hi.z, (_Float16)hi.w};
            }
        }
    }
#pragma unroll
    for (int s = 0; s < 4; ++s)
#pragma unroll
        for (int u = 0; u < 2; ++u)
#pragma unroll
            for (int kt = 0; kt < 4; ++kt) pin_agpr(bf[s][u][kt]);

    if (tid < TH) h_lds[0][tid] = (_Float16)0.f;

    float c_state = 0.0f;
    float h_keep  = 0.0f;

    // gx ring: [slot][gate], per-lane base at this lane's channel
    gcfp gxp = (gcfp)(gx + (size_t)b * TT * TG + ch);
    float gr[4][4];
#pragma unroll
    for (int sl = 0; sl < 4; ++sl) {
#pragma unroll
        for (int s = 0; s < 4; ++s)
            gr[sl][s] = gxp[(size_t)sl * TG + s * TH];
    }
    gxp += 4 * (size_t)TG;

    gfp yp = (gfp)(y + (size_t)b * TT * TH + ch);

    __syncthreads();

    const f32x4 kz = {0.f, 0.f, 0.f, 0.f};

#define STEP(SLOT, CUR, NXT)                                                   \
    {                                                                          \
        f16x8 a0 = *(const f16x8*)&h_lds[CUR][0 * 32 + oct * 8];               \
        f16x8 a1 = *(const f16x8*)&h_lds[CUR][1 * 32 + oct * 8];               \
        f16x8 a2 = *(const f16x8*)&h_lds[CUR][2 * 32 + oct * 8];               \
        f16x8 a3 = *(const f16x8*)&h_lds[CUR][3 * 32 + oct * 8];               \
        float pv[4][2];                                                        \
        _Pragma("unroll")                                                      \
        for (int s = 0; s < 4; ++s) {                                          \
            _Pragma("unroll")                                                  \
            for (int u = 0; u < 2; ++u) {                                      \
                f32x4 qa = __builtin_amdgcn_mfma_f32_16x16x32_f16(             \
                    a0, bf[s][u][0], kz, 0, 0, 0);                             \
                qa = __builtin_amdgcn_mfma_f32_16x16x32_f16(                   \
                    a1, bf[s][u][1], qa, 0, 0, 0);                             \
                f32x4 qb = __builtin_amdgcn_mfma_f32_16x16x32_f16(             \
                    a2, bf[s][u][2], kz, 0, 0, 0);                             \
                qb = __builtin_amdgcn_mfma_f32_16x16x32_f16(                   \
                    a3, bf[s][u][3], qb, 0, 0, 0);                             \
                pv[s][u] = qa[0] + qb[0];                                      \
            }                                                                  \
        }                                                                      \
        const float p0 = (uu ? pv[0][1] : pv[0][0]) + gr[SLOT][0];             \
        const float p1 = (uu ? pv[1][1] : pv[1][0]) + gr[SLOT][1];             \
        const float p2 = (uu ? pv[2][1] : pv[2][0]) + gr[SLOT][2];             \
        const float p3 = (uu ? pv[3][1] : pv[3][0]) + gr[SLOT][3];             \
        gr[SLOT][0] = gxp[0 * TH];                                             \
        gr[SLOT][1] = gxp[1 * TH];                                             \
        gr[SLOT][2] = gxp[2 * TH];                                             \
        gr[SLOT][3] = gxp[3 * TH];                                             \
        gxp += TG;                                                             \
        const float gi = sigf(p0);                                             \
        const float gf = sigf(p1);                                             \
        const float gg = tanhf_fast(p2);                                       \
        const float go = sigf(p3);                                             \
        c_state = fmaf(gf, c_state, gi * gg);                                  \
        h_keep  = go * tanhf_fast(c_state);                                    \
        if (lane < 32) {                                                       \
            h_lds[NXT][ch] = (_Float16)h_keep;                                 \
            *yp = h_keep;                                                      \
        }                                                                      \
        yp += TH;                                                              \
        asm volatile("s_waitcnt lgkmcnt(0)" ::: "memory");                     \
        __builtin_amdgcn_s_barrier();                                          \
    }

#pragma unroll 1
    for (int t = 0; t < TT; t += 4) {
        STEP(0, 0, 1)
        STEP(1, 1, 0)
        STEP(2, 0, 1)
        STEP(3, 1, 0)
    }
#undef STEP

    if (lane < 32) {
        ((gfp)(hn))[(size_t)b * TH + ch] = h_keep;
        ((gfp)(cn))[(size_t)b * TH + ch] = c_state;
    }
}

// ---------------------------------------------------------------------------
// PROBE: same 4-wave kernel, NO gx loads, 1.5x steps (24576) so it lands in
// the top-5 with its own counters (direct read). Writes only into workspace.
// ---------------------------------------------------------------------------
#define PTT 24576
__global__
__attribute__((amdgpu_flat_work_group_size(256, 256), amdgpu_waves_per_eu(1, 1)))
void probe_nogx4(const float* __restrict__ W_hh, float* __restrict__ yout)
{
    const int b    = blockIdx.x;
    const int tid  = threadIdx.x;
    const int w    = tid >> 6;
    const int lane = tid & 63;
    const int c    = lane & 15;
    const int oct  = lane >> 4;
    const int uu   = oct & 1;
    const int ch   = 32 * w + 16 * uu + c;

    __shared__ __align__(16) _Float16 h_lds[2][TH];

    f16x8 bf[4][2][4];
#pragma unroll
    for (int s = 0; s < 4; ++s) {
#pragma unroll
        for (int u = 0; u < 2; ++u) {
#pragma unroll
            for (int kt = 0; kt < 4; ++kt) {
                const float* wr = W_hh +
                    (size_t)(s * TH + 32 * w + 16 * u + c) * TH + kt * 32 + oct * 8;
                const float4 lo = ld4(wr);
                const float4 hi = ld4(wr + 4);
                bf[s][u][kt] = f16x8{(_Float16)lo.x, (_Float16)lo.y,
                                     (_Float16)lo.z, (_Float16)lo.w,
                                     (_Float16)hi.x, (_Float16)hi.y,
                                     (_Float16)hi.z, (_Float16)hi.w};
            }
        }
    }
#pragma unroll
    for (int s = 0; s < 4; ++s)
#pragma unroll
        for (int u = 0; u < 2; ++u)
#pragma unroll
            for (int kt = 0; kt < 4; ++kt) pin_agpr(bf[s][u][kt]);

    if (tid < TH) h_lds[0][tid] = (_Float16)0.f;

    float c_state = 0.0f;
    float h_keep  = 0.0f;
    float g0 = 0.11f, g1 = -0.07f, g2 = 0.05f, g3 = -0.13f;
    asm volatile("" : "+v"(g0), "+v"(g1), "+v"(g2), "+v"(g3));

    gfp yp = (gfp)(yout + (size_t)b * PTT * TH + ch);

    __syncthreads();

    const f32x4 kz = {0.f, 0.f, 0.f, 0.f};

#define PSTEP(CUR, NXT)                                                        \
    {                                                                          \
        f16x8 a0 = *(const f16x8*)&h_lds[CUR][0 * 32 + oct * 8];               \
        f16x8 a1 = *(const f16x8*)&h_lds[CUR][1 * 32 + oct * 8];               \
        f16x8 a2 = *(const f16x8*)&h_lds[CUR][2 * 32 + oct * 8];               \
        f16x8 a3 = *(const f16x8*)&h_lds[CUR][3 * 32 + oct * 8];               \
        float pv[4][2];                                                        \
        _Pragma("unroll")                                                      \
        for (int s = 0; s < 4; ++s) {                                          \
            _Pragma("unroll")                                                  \
            for (int u = 0; u < 2; ++u) {                                      \
                f32x4 qa = __builtin_amdgcn_mfma_f32_16x16x32_f16(             \
                    a0, bf[s][u][0], kz, 0, 0, 0);                             \
                qa = __builtin_amdgcn_mfma_f32_16x16x32_f16(                   \
                    a1, bf[s][u][1], qa, 0, 0, 0);                             \
                f32x4 qb = __builtin_amdgcn_mfma_f32_16x16x32_f16(             \
                    a2, bf[s][u][2], kz, 0, 0, 0);                             \
                qb = __builtin_amdgcn_mfma_f32_16x16x32_f16(                   \
                    a3, bf[s][u][3], qb, 0, 0, 0);                             \
                pv[s][u] = qa[0] + qb[0];                                      \
            }                                                                  \
        }                                                                      \
        const float p0 = (uu ? pv[0][1] : pv[0][0]) + g0;                      \
        const float p1 = (uu ? pv[1][1] : pv[1][0]) + g1;                      \
        const float p2 = (uu ? pv[2][1] : pv[2][0]) + g2;                      \
        const float p3 = (uu ? pv[3][1] : pv[3][0]) + g3;                      \
        const float gi = sigf(p0);                                             \
        const float gf = sigf(p1);                                             \
        const float gg = tanhf_fast(p2);                                       \
        const float go = sigf(p3);                                             \
        c_state = fmaf(gf, c_state, gi * gg);                                  \
        h_keep  = go * tanhf_fast(c_state);                                    \
        if (lane < 32) {                                                       \
            h_lds[NXT][ch] = (_Float16)h_keep;                                 \
            *yp = h_keep;                                                      \
        }                                                                      \
        yp += TH;                                                              \
        asm volatile("s_waitcnt lgkmcnt(0)" ::: "memory");                     \
        __builtin_amdgcn_s_barrier();                                          \
    }

#pragma unroll 1
    for (int t = 0; t < PTT; t += 2) {
        PSTEP(0, 1)
        PSTEP(1, 0)
    }
#undef PSTEP

    if (lane < 32) {
        gfp hp = (gfp)(yout + (size_t)TB * PTT * TH);
        hp[(size_t)b * TH + ch] = h_keep;
        hp[(size_t)TB * TH + (size_t)b * TH + ch] = c_state;
    }
}

// ---------------------------------------------------------------------------
// Fallback scan (no workspace): f32, recomputes x-projection on the fly.
// ---------------------------------------------------------------------------
__global__ __launch_bounds__(512, 2) void lstm_scan_fused(
    const float* __restrict__ x, const float* __restrict__ W_ih,
    const float* __restrict__ W_hh, const float* __restrict__ b_ih,
    const float* __restrict__ b_hh,
    float* __restrict__ y, float* __restrict__ hn, float* __restrict__ cn)
{
    const int b    = blockIdx.x;
    const int tid  = threadIdx.x;
    const int j    = tid & (TH - 1);
    const int gate = tid >> 7;

    __shared__ __align__(16) float h_lds[TH];
    __shared__ __align__(16) float g_lds[TG];
    __shared__ __align__(16) float xs[2][TI];

    float4 w[TH / 4];
#pragma unroll
    for (int k4 = 0; k4 < TH / 4; ++k4)
        w[k4] = ld4(W_hh + (size_t)tid * TH + k4 * 4);
    float4 u[TI / 4];
#pragma unroll
    for (int k4 = 0; k4 < TI / 4; ++k4)
        u[k4] = ld4(W_ih + (size_t)tid * TI + k4 * 4);
    const float bias = b_ih[tid] + b_hh[tid];

    if (tid < TH) h_lds[tid] = 0.0f;
    float c_state = 0.0f;
    float h_keep  = 0.0f;

    float4 xreg = make_float4(0.f, 0.f, 0.f, 0.f);
    const float* xp = x + ((size_t)b * TT + 2) * TI;
    float* yp = y + (size_t)b * TT * TH;

    if (tid < TI / 4)
        *reinterpret_cast<float4*>(&xs[0][tid * 4]) =
            ld4(x + ((size_t)b * TT + 0) * TI + tid * 4);
    __syncthreads();
    if (tid < TI / 4)
        xreg = ld4(x + ((size_t)b * TT + 1) * TI + tid * 4);

#pragma unroll 1
    for (int t = 0; t < TT; ++t) {
        float4 acc = make_float4(0.f, 0.f, 0.f, 0.f);
#pragma unroll
        for (int k4 = 0; k4 < TH / 4; ++k4) {
            const float4 h4 = *reinterpret_cast<const float4*>(&h_lds[k4 * 4]);
            fma4(acc, w[k4], h4);
        }
        float p = hsum4(acc);
        {
            float4 fx = make_float4(0.f, 0.f, 0.f, 0.f);
            const float* xrow = xs[t & 1];
#pragma unroll
            for (int k4 = 0; k4 < TI / 4; ++k4) {
                const float4 x4 = *reinterpret_cast<const float4*>(&xrow[k4 * 4]);
                fma4(fx, u[k4], x4);
            }
            p += hsum4(fx) + bias;
        }

        const float act = (gate == 2) ? tanhf_fast(p) : sigf(p);
        g_lds[tid] = act;

        asm volatile("s_waitcnt lgkmcnt(0)" ::: "memory");
        __builtin_amdgcn_s_barrier();

        if (tid < TH) {
            const float gi = g_lds[j];
            const float gf = g_lds[TH + j];
            const float gg = g_lds[2 * TH + j];
            const float go = g_lds[3 * TH + j];
            c_state = fmaf(gf, c_state, gi * gg);
            h_keep  = go * tanhf_fast(c_state);
            h_lds[j] = h_keep;
            yp[(size_t)t * TH + j] = h_keep;
        }

        if (tid < TI / 4) {
            if (t + 1 < TT)
                *reinterpret_cast<float4*>(&xs[(t + 1) & 1][tid * 4]) = xreg;
            if (t + 2 < TT) xreg = ld4(xp + tid * 4);
        }
        xp += TI;

        asm volatile("s_waitcnt lgkmcnt(0)" ::: "memory");
        __builtin_amdgcn_s_barrier();
    }

    if (tid < TH) {
        hn[(size_t)b * TH + j] = h_keep;
        cn[(size_t)b * TH + j] = c_state;
    }
}

// ---------------------------------------------------------------------------
// BatchNorm over flattened [B*T, H] + LeakyReLU
// ---------------------------------------------------------------------------
__global__ void bn_zero(float* ws) { ws[threadIdx.x] = 0.0f; }

__global__ __launch_bounds__(256) void bn_stats(const float* __restrict__ y,
                                                float* __restrict__ ws)
{
    const int tid  = threadIdx.x;
    const int col4 = tid & 31;
    const int rg   = tid >> 5;
    const int NROW = TB * TT;
    float4 s = make_float4(0.f, 0.f, 0.f, 0.f);
    float4 q = make_float4(0.f, 0.f, 0.f, 0.f);
    for (int row = blockIdx.x * 8 + rg; row < NROW; row += gridDim.x * 8) {
        const float4 v = ld4(y + (size_t)row * TH + col4 * 4);
        s.x += v.x; s.y += v.y; s.z += v.z; s.w += v.w;
        q.x = fmaf(v.x, v.x, q.x); q.y = fmaf(v.y, v.y, q.y);
        q.z = fmaf(v.z, v.z, q.z); q.w = fmaf(v.w, v.w, q.w);
    }
    __shared__ float4 ls[256], lq[256];
    ls[tid] = s; lq[tid] = q;
    __syncthreads();
    if (tid < 32) {
        float4 S = ls[tid], Q = lq[tid];
        for (int g2 = 1; g2 < 8; ++g2) {
            const float4 a = ls[g2 * 32 + tid], b2 = lq[g2 * 32 + tid];
            S.x += a.x; S.y += a.y; S.z += a.z; S.w += a.w;
            Q.x += b2.x; Q.y += b2.y; Q.z += b2.z; Q.w += b2.w;
        }
        atomicAdd(&ws[tid * 4 + 0], S.x); atomicAdd(&ws[tid * 4 + 1], S.y);
        atomicAdd(&ws[tid * 4 + 2], S.z); atomicAdd(&ws[tid * 4 + 3], S.w);
        atomicAdd(&ws[TH + tid * 4 + 0], Q.x); atomicAdd(&ws[TH + tid * 4 + 1], Q.y);
        atomicAdd(&ws[TH + tid * 4 + 2], Q.z); atomicAdd(&ws[TH + tid * 4 + 3], Q.w);
    }
}

__global__ __launch_bounds__(256) void bn_apply(float* __restrict__ y,
                                                const float* __restrict__ ws,
                                                const float* __restrict__ gamma,
                                                const float* __restrict__ beta)
{
    const int tid  = threadIdx.x;
    const int col4 = tid & 31;
    const int rg   = tid >> 5;
    const int NROW = TB * TT;
    const float invN = 1.0f / (float)(TB * TT);

    const float4 sm = ld4(ws + col4 * 4);
    const float4 sq = ld4(ws + TH + col4 * 4);
    const float4 gm = ld4(gamma + col4 * 4);
    const float4 bt = ld4(beta + col4 * 4);
    float4 mean, scale, shift;
    mean.x = sm.x * invN; mean.y = sm.y * invN;
    mean.z = sm.z * invN; mean.w = sm.w * invN;
    scale.x = rsqrtf(fmaf(-mean.x, mean.x, sq.x * invN) + 1e-5f) * gm.x;
    scale.y = rsqrtf(fmaf(-mean.y, mean.y, sq.y * invN) + 1e-5f) * gm.y;
    scale.z = rsqrtf(fmaf(-mean.z, mean.z, sq.z * invN) + 1e-5f) * gm.z;
    scale.w = rsqrtf(fmaf(-mean.w, mean.w, sq.w * invN) + 1e-5f) * gm.w;
    shift.x = bt.x - mean.x * scale.x; shift.y = bt.y - mean.y * scale.y;
    shift.z = bt.z - mean.z * scale.z; shift.w = bt.w - mean.w * scale.w;

    for (int row = blockIdx.x * 8 + rg; row < NROW; row += gridDim.x * 8) {
        float* p = y + (size_t)row * TH + col4 * 4;
        float4 v = *reinterpret_cast<const float4*>(p);
        v.x = fmaf(v.x, scale.x, shift.x); v.y = fmaf(v.y, scale.y, shift.y);
        v.z = fmaf(v.z, scale.z, shift.z); v.w = fmaf(v.w, scale.w, shift.w);
        v.x = fmaxf(v.x, 0.01f * v.x); v.y = fmaxf(v.y, 0.01f * v.y);
        v.z = fmaxf(v.z, 0.01f * v.z); v.w = fmaxf(v.w, 0.01f * v.w);
        *reinterpret_cast<float4*>(p) = v;
    }
}

// ---------------------------------------------------------------------------
extern "C" void kernel_launch(void* const* d_in, const int* in_sizes, int n_in,
                              void* d_out, int out_size, void* d_ws, size_t ws_size,
                              hipStream_t stream)
{
    const float* x     = (const float*)d_in[0];
    const float* W_ih  = (const float*)d_in[1];
    const float* W_hh  = (const float*)d_in[2];
    const float* b_ih  = (const float*)d_in[3];
    const float* b_hh  = (const float*)d_in[4];
    const float* gamma = (const float*)d_in[5];
    const float* beta  = (const float*)d_in[6];

    float* y  = (float*)d_out;
    float* hn = y + (size_t)TB * TT * TH;
    float* cn = hn + TB * TH;

    float* ws_stats = (float*)d_ws;
    const size_t GX_BYTES = (size_t)TB * TT * TG * sizeof(float);
    const bool use_ws = ws_size >= GX_BYTES + 4096 + 4 * TG * sizeof(float);

    bn_zero<<<1, 256, 0, stream>>>(ws_stats);

    if (use_ws) {
        float* gxbuf = (float*)((char*)d_ws + 4096);
        gx_precompute<<<2048, 256, 0, stream>>>(x, W_ih, b_ih, b_hh, gxbuf);
        lstm_scan_mfma4<<<TB, 256, 0, stream>>>(W_hh, gxbuf, y, hn, cn);
        // diagnosis probe: no-gx variant at 1.5x steps -> lands in top-5 with
        // its own counters; writes only into the already-consumed gx region.
        probe_nogx4<<<TB, 256, 0, stream>>>(W_hh, gxbuf);
    } else {
        lstm_scan_fused<<<TB, 512, 0, stream>>>(x, W_ih, W_hh, b_ih, b_hh,
                                                y, hn, cn);
    }

    bn_stats<<<512, 256, 0, stream>>>(y, ws_stats);
    bn_apply<<<2048, 256, 0, stream>>>(y, ws_stats, gamma, beta);
}

// Round 14
// 9040.126 us; speedup vs baseline: 2.4768x; 2.4768x over previous
//
#include <hip/hip_runtime.h>
#include <hip/hip_bf16.h>
#include <cstdint>

#define TB 16
#define TT 16384
#define TI 64
#define TH 128
#define TG 512  // 4*H

typedef _Float16 f16x8 __attribute__((ext_vector_type(8)));
typedef float    f32x4 __attribute__((ext_vector_type(4)));

typedef const float __attribute__((address_space(1)))* gcfp;
typedef float __attribute__((address_space(1)))*       gfp;

__device__ __forceinline__ float sigf(float z) {
    return 1.0f / (1.0f + __expf(-z));
}
__device__ __forceinline__ float tanhf_fast(float z) {
    return 2.0f / (1.0f + __expf(-2.0f * z)) - 1.0f;
}
__device__ __forceinline__ float4 ld4(const float* p) {
    return *reinterpret_cast<const float4*>(p);
}
__device__ __forceinline__ void fma4(float4& acc, const float4 w, const float4 h) {
    acc.x = fmaf(w.x, h.x, acc.x);
    acc.y = fmaf(w.y, h.y, acc.y);
    acc.z = fmaf(w.z, h.z, acc.z);
    acc.w = fmaf(w.w, h.w, acc.w);
}
__device__ __forceinline__ float hsum4(const float4 a) {
    return (a.x + a.y) + (a.z + a.w);
}
__device__ __forceinline__ void pin_agpr(f16x8& v) {
    asm volatile("" : "+a"(v));
}

// ---------------------------------------------------------------------------
// gx = x @ W_ih^T + b_ih + b_hh
// ---------------------------------------------------------------------------
__global__ __launch_bounds__(256, 2) void gx_precompute(
    const float* __restrict__ x, const float* __restrict__ W_ih,
    const float* __restrict__ b_ih, const float* __restrict__ b_hh,
    float* __restrict__ gx)
{
    const int tid  = threadIdx.x;
    const int j    = tid & (TH - 1);
    const int pair = tid >> 7;
    const int row_a = pair * 2 * TH + j;
    const int row_b = row_a + TH;

    float4 ua[TI / 4], ub[TI / 4];
#pragma unroll
    for (int k4 = 0; k4 < TI / 4; ++k4) {
        ua[k4] = ld4(W_ih + (size_t)row_a * TI + k4 * 4);
        ub[k4] = ld4(W_ih + (size_t)row_b * TI + k4 * 4);
    }
    const float bias_a = b_ih[row_a] + b_hh[row_a];
    const float bias_b = b_ih[row_b] + b_hh[row_b];

    __shared__ __align__(16) float xs[2][TI];
    const int ROWS = 128;
    const size_t r0 = (size_t)blockIdx.x * ROWS;

    if (tid < TI / 4)
        *reinterpret_cast<float4*>(&xs[0][tid * 4]) = ld4(x + r0 * TI + tid * 4);
    __syncthreads();
    float4 xreg = make_float4(0.f, 0.f, 0.f, 0.f);
    if (tid < TI / 4) xreg = ld4(x + (r0 + 1) * TI + tid * 4);

#pragma unroll 1
    for (int rr = 0; rr < ROWS; ++rr) {
        const float* xrow = xs[rr & 1];
        float4 aa = make_float4(0.f, 0.f, 0.f, 0.f);
        float4 ab = make_float4(0.f, 0.f, 0.f, 0.f);
#pragma unroll
        for (int k4 = 0; k4 < TI / 4; ++k4) {
            const float4 x4 = *reinterpret_cast<const float4*>(&xrow[k4 * 4]);
            fma4(aa, ua[k4], x4);
            fma4(ab, ub[k4], x4);
        }
        if (tid < TI / 4) {
            if (rr + 1 < ROWS)
                *reinterpret_cast<float4*>(&xs[(rr + 1) & 1][tid * 4]) = xreg;
            if (rr + 2 < ROWS) xreg = ld4(x + (r0 + rr + 2) * TI + tid * 4);
        }
        float* grow = gx + (r0 + rr) * (size_t)TG;
        grow[row_a] = hsum4(aa) + bias_a;
        grow[row_b] = hsum4(ab) + bias_b;

        asm volatile("s_waitcnt lgkmcnt(0)" ::: "memory");
        __builtin_amdgcn_s_barrier();
    }
}

// ---------------------------------------------------------------------------
// MFMA LSTM scan v13: 320 threads = 4 compute waves + 1 gx-producer wave.
// Compute waves: R12 structure (wave w owns channels [32w,32w+32), redundant
// A-trick, 32 MFMA/wave, h f16 double-buffered in LDS, 1 barrier/step) but
// gx now arrives via an LDS ring filled by the producer wave, so consumer
// waves carry NO loop-carried global loads (their only vm op is the y store,
// which nothing waits on). Producer per step: ds_write row t+1 from regs,
// then load row t+2 (use-distance = 1 full step ~1200cyc -> its compiler-
// inserted vmcnt wait never stalls).
// ---------------------------------------------------------------------------
__global__
__attribute__((amdgpu_flat_work_group_size(320, 320), amdgpu_waves_per_eu(1, 2)))
void lstm_scan_mfma5(
    const float* __restrict__ W_hh, const float* __restrict__ gx,
    float* __restrict__ y, float* __restrict__ hn, float* __restrict__ cn)
{
    const int b    = blockIdx.x;
    const int tid  = threadIdx.x;
    const int w    = tid >> 6;        // wave 0..4 (4 = producer)
    const int lane = tid & 63;
    const int c    = lane & 15;
    const int oct  = lane >> 4;
    const int uu   = oct & 1;
    const int ch   = 32 * (w & 3) + 16 * uu + c;

    __shared__ __align__(16) _Float16 h_lds[2][TH];
    __shared__ __align__(16) float    gx_lds[2][TG];

    float c_state = 0.0f;
    float h_keep  = 0.0f;

    f16x8 bf[4][2][4];
    float4 va, vb;
    const float4* g4 = reinterpret_cast<const float4*>(gx + (size_t)b * TT * TG);

    if (w < 4) {
        // B fragments (consumer waves only)
#pragma unroll
        for (int s = 0; s < 4; ++s) {
#pragma unroll
            for (int u = 0; u < 2; ++u) {
#pragma unroll
                for (int kt = 0; kt < 4; ++kt) {
                    const float* wr = W_hh +
                        (size_t)(s * TH + 32 * w + 16 * u + c) * TH + kt * 32 + oct * 8;
                    const float4 lo = ld4(wr);
                    const float4 hi = ld4(wr + 4);
                    bf[s][u][kt] = f16x8{(_Float16)lo.x, (_Float16)lo.y,
                                         (_Float16)lo.z, (_Float16)lo.w,
                                         (_Float16)hi.x, (_Float16)hi.y,
                                         (_Float16)hi.z, (_Float16)hi.w};
                }
            }
        }
#pragma unroll
        for (int s = 0; s < 4; ++s)
#pragma unroll
            for (int u = 0; u < 2; ++u)
#pragma unroll
                for (int kt = 0; kt < 4; ++kt) pin_agpr(bf[s][u][kt]);

        if (tid < TH) h_lds[0][tid] = (_Float16)0.f;
    } else {
        // producer prologue: fill slot 0 (t=0), preload t=1 into regs
        va = g4[lane];
        vb = g4[lane + 64];
        *reinterpret_cast<float4*>(&gx_lds[0][lane * 4])       = va;
        *reinterpret_cast<float4*>(&gx_lds[0][256 + lane * 4]) = vb;
        va = g4[128 + lane];
        vb = g4[128 + lane + 64];
        g4 += 256;   // now at t=2
    }

    asm volatile("s_waitcnt lgkmcnt(0)" ::: "memory");
    __builtin_amdgcn_s_barrier();

    const f32x4 kz = {0.f, 0.f, 0.f, 0.f};

    if (w < 4) {
        gfp yp = (gfp)(y + (size_t)b * TT * TH + ch);

#define CSTEP(S)                                                               \
    {                                                                          \
        f16x8 a0 = *(const f16x8*)&h_lds[S][0 * 32 + oct * 8];                 \
        f16x8 a1 = *(const f16x8*)&h_lds[S][1 * 32 + oct * 8];                 \
        f16x8 a2 = *(const f16x8*)&h_lds[S][2 * 32 + oct * 8];                 \
        f16x8 a3 = *(const f16x8*)&h_lds[S][3 * 32 + oct * 8];                 \
        const float g0 = gx_lds[S][0 * TH + ch];                               \
        const float g1 = gx_lds[S][1 * TH + ch];                               \
        const float g2 = gx_lds[S][2 * TH + ch];                               \
        const float g3 = gx_lds[S][3 * TH + ch];                               \
        float pv[4][2];                                                        \
        _Pragma("unroll")                                                      \
        for (int s = 0; s < 4; ++s) {                                          \
            _Pragma("unroll")                                                  \
            for (int u = 0; u < 2; ++u) {                                      \
                f32x4 qa = __builtin_amdgcn_mfma_f32_16x16x32_f16(             \
                    a0, bf[s][u][0], kz, 0, 0, 0);                             \
                qa = __builtin_amdgcn_mfma_f32_16x16x32_f16(                   \
                    a1, bf[s][u][1], qa, 0, 0, 0);                             \
                f32x4 qb = __builtin_amdgcn_mfma_f32_16x16x32_f16(             \
                    a2, bf[s][u][2], kz, 0, 0, 0);                             \
                qb = __builtin_amdgcn_mfma_f32_16x16x32_f16(                   \
                    a3, bf[s][u][3], qb, 0, 0, 0);                             \
                pv[s][u] = qa[0] + qb[0];                                      \
            }                                                                  \
        }                                                                      \
        const float p0 = (uu ? pv[0][1] : pv[0][0]) + g0;                      \
        const float p1 = (uu ? pv[1][1] : pv[1][0]) + g1;                      \
        const float p2 = (uu ? pv[2][1] : pv[2][0]) + g2;                      \
        const float p3 = (uu ? pv[3][1] : pv[3][0]) + g3;                      \
        const float gi = sigf(p0);                                             \
        const float gf = sigf(p1);                                             \
        const float gg = tanhf_fast(p2);                                       \
        const float go = sigf(p3);                                             \
        c_state = fmaf(gf, c_state, gi * gg);                                  \
        h_keep  = go * tanhf_fast(c_state);                                    \
        if (lane < 32) {                                                       \
            h_lds[S ^ 1][ch] = (_Float16)h_keep;                               \
            *yp = h_keep;                                                      \
        }                                                                      \
        yp += TH;                                                              \
        asm volatile("s_waitcnt lgkmcnt(0)" ::: "memory");                     \
        __builtin_amdgcn_s_barrier();                                          \
    }

#pragma unroll 1
        for (int t = 0; t < TT; t += 2) {
            CSTEP(0)
            CSTEP(1)
        }
#undef CSTEP

        if (lane < 32) {
            ((gfp)(hn))[(size_t)b * TH + ch] = h_keep;
            ((gfp)(cn))[(size_t)b * TH + ch] = c_state;
        }
    } else {
#define PSTEP(S)                                                               \
    {                                                                          \
        /* write slot S^1 (row t+1) from regs; then load row t+2 */            \
        *reinterpret_cast<float4*>(&gx_lds[S ^ 1][lane * 4])       = va;       \
        *reinterpret_cast<float4*>(&gx_lds[S ^ 1][256 + lane * 4]) = vb;       \
        va = g4[lane];                                                         \
        vb = g4[lane + 64];                                                    \
        g4 += 128;                                                             \
        asm volatile("s_waitcnt lgkmcnt(0)" ::: "memory");                     \
        __builtin_amdgcn_s_barrier();                                          \
    }

#pragma unroll 1
        for (int t = 0; t < TT; t += 2) {
            PSTEP(0)
            PSTEP(1)
        }
#undef PSTEP
    }
}

// ---------------------------------------------------------------------------
// Fallback scan (no workspace): f32, recomputes x-projection on the fly.
// ---------------------------------------------------------------------------
__global__ __launch_bounds__(512, 2) void lstm_scan_fused(
    const float* __restrict__ x, const float* __restrict__ W_ih,
    const float* __restrict__ W_hh, const float* __restrict__ b_ih,
    const float* __restrict__ b_hh,
    float* __restrict__ y, float* __restrict__ hn, float* __restrict__ cn)
{
    const int b    = blockIdx.x;
    const int tid  = threadIdx.x;
    const int j    = tid & (TH - 1);
    const int gate = tid >> 7;

    __shared__ __align__(16) float h_lds[TH];
    __shared__ __align__(16) float g_lds[TG];
    __shared__ __align__(16) float xs[2][TI];

    float4 w[TH / 4];
#pragma unroll
    for (int k4 = 0; k4 < TH / 4; ++k4)
        w[k4] = ld4(W_hh + (size_t)tid * TH + k4 * 4);
    float4 u[TI / 4];
#pragma unroll
    for (int k4 = 0; k4 < TI / 4; ++k4)
        u[k4] = ld4(W_ih + (size_t)tid * TI + k4 * 4);
    const float bias = b_ih[tid] + b_hh[tid];

    if (tid < TH) h_lds[tid] = 0.0f;
    float c_state = 0.0f;
    float h_keep  = 0.0f;

    float4 xreg = make_float4(0.f, 0.f, 0.f, 0.f);
    const float* xp = x + ((size_t)b * TT + 2) * TI;
    float* yp = y + (size_t)b * TT * TH;

    if (tid < TI / 4)
        *reinterpret_cast<float4*>(&xs[0][tid * 4]) =
            ld4(x + ((size_t)b * TT + 0) * TI + tid * 4);
    __syncthreads();
    if (tid < TI / 4)
        xreg = ld4(x + ((size_t)b * TT + 1) * TI + tid * 4);

#pragma unroll 1
    for (int t = 0; t < TT; ++t) {
        float4 acc = make_float4(0.f, 0.f, 0.f, 0.f);
#pragma unroll
        for (int k4 = 0; k4 < TH / 4; ++k4) {
            const float4 h4 = *reinterpret_cast<const float4*>(&h_lds[k4 * 4]);
            fma4(acc, w[k4], h4);
        }
        float p = hsum4(acc);
        {
            float4 fx = make_float4(0.f, 0.f, 0.f, 0.f);
            const float* xrow = xs[t & 1];
#pragma unroll
            for (int k4 = 0; k4 < TI / 4; ++k4) {
                const float4 x4 = *reinterpret_cast<const float4*>(&xrow[k4 * 4]);
                fma4(fx, u[k4], x4);
            }
            p += hsum4(fx) + bias;
        }

        const float act = (gate == 2) ? tanhf_fast(p) : sigf(p);
        g_lds[tid] = act;

        asm volatile("s_waitcnt lgkmcnt(0)" ::: "memory");
        __builtin_amdgcn_s_barrier();

        if (tid < TH) {
            const float gi = g_lds[j];
            const float gf = g_lds[TH + j];
            const float gg = g_lds[2 * TH + j];
            const float go = g_lds[3 * TH + j];
            c_state = fmaf(gf, c_state, gi * gg);
            h_keep  = go * tanhf_fast(c_state);
            h_lds[j] = h_keep;
            yp[(size_t)t * TH + j] = h_keep;
        }

        if (tid < TI / 4) {
            if (t + 1 < TT)
                *reinterpret_cast<float4*>(&xs[(t + 1) & 1][tid * 4]) = xreg;
            if (t + 2 < TT) xreg = ld4(xp + tid * 4);
        }
        xp += TI;

        asm volatile("s_waitcnt lgkmcnt(0)" ::: "memory");
        __builtin_amdgcn_s_barrier();
    }

    if (tid < TH) {
        hn[(size_t)b * TH + j] = h_keep;
        cn[(size_t)b * TH + j] = c_state;
    }
}

// ---------------------------------------------------------------------------
// BatchNorm over flattened [B*T, H] + LeakyReLU
// ---------------------------------------------------------------------------
__global__ void bn_zero(float* ws) { ws[threadIdx.x] = 0.0f; }

__global__ __launch_bounds__(256) void bn_stats(const float* __restrict__ y,
                                                float* __restrict__ ws)
{
    const int tid  = threadIdx.x;
    const int col4 = tid & 31;
    const int rg   = tid >> 5;
    const int NROW = TB * TT;
    float4 s = make_float4(0.f, 0.f, 0.f, 0.f);
    float4 q = make_float4(0.f, 0.f, 0.f, 0.f);
    for (int row = blockIdx.x * 8 + rg; row < NROW; row += gridDim.x * 8) {
        const float4 v = ld4(y + (size_t)row * TH + col4 * 4);
        s.x += v.x; s.y += v.y; s.z += v.z; s.w += v.w;
        q.x = fmaf(v.x, v.x, q.x); q.y = fmaf(v.y, v.y, q.y);
        q.z = fmaf(v.z, v.z, q.z); q.w = fmaf(v.w, v.w, q.w);
    }
    __shared__ float4 ls[256], lq[256];
    ls[tid] = s; lq[tid] = q;
    __syncthreads();
    if (tid < 32) {
        float4 S = ls[tid], Q = lq[tid];
        for (int g2 = 1; g2 < 8; ++g2) {
            const float4 a = ls[g2 * 32 + tid], b2 = lq[g2 * 32 + tid];
            S.x += a.x; S.y += a.y; S.z += a.z; S.w += a.w;
            Q.x += b2.x; Q.y += b2.y; Q.z += b2.z; Q.w += b2.w;
        }
        atomicAdd(&ws[tid * 4 + 0], S.x); atomicAdd(&ws[tid * 4 + 1], S.y);
        atomicAdd(&ws[tid * 4 + 2], S.z); atomicAdd(&ws[tid * 4 + 3], S.w);
        atomicAdd(&ws[TH + tid * 4 + 0], Q.x); atomicAdd(&ws[TH + tid * 4 + 1], Q.y);
        atomicAdd(&ws[TH + tid * 4 + 2], Q.z); atomicAdd(&ws[TH + tid * 4 + 3], Q.w);
    }
}

__global__ __launch_bounds__(256) void bn_apply(float* __restrict__ y,
                                                const float* __restrict__ ws,
                                                const float* __restrict__ gamma,
                                                const float* __restrict__ beta)
{
    const int tid  = threadIdx.x;
    const int col4 = tid & 31;
    const int rg   = tid >> 5;
    const int NROW = TB * TT;
    const float invN = 1.0f / (float)(TB * TT);

    const float4 sm = ld4(ws + col4 * 4);
    const float4 sq = ld4(ws + TH + col4 * 4);
    const float4 gm = ld4(gamma + col4 * 4);
    const float4 bt = ld4(beta + col4 * 4);
    float4 mean, scale, shift;
    mean.x = sm.x * invN; mean.y = sm.y * invN;
    mean.z = sm.z * invN; mean.w = sm.w * invN;
    scale.x = rsqrtf(fmaf(-mean.x, mean.x, sq.x * invN) + 1e-5f) * gm.x;
    scale.y = rsqrtf(fmaf(-mean.y, mean.y, sq.y * invN) + 1e-5f) * gm.y;
    scale.z = rsqrtf(fmaf(-mean.z, mean.z, sq.z * invN) + 1e-5f) * gm.z;
    scale.w = rsqrtf(fmaf(-mean.w, mean.w, sq.w * invN) + 1e-5f) * gm.w;
    shift.x = bt.x - mean.x * scale.x; shift.y = bt.y - mean.y * scale.y;
    shift.z = bt.z - mean.z * scale.z; shift.w = bt.w - mean.w * scale.w;

    for (int row = blockIdx.x * 8 + rg; row < NROW; row += gridDim.x * 8) {
        float* p = y + (size_t)row * TH + col4 * 4;
        float4 v = *reinterpret_cast<const float4*>(p);
        v.x = fmaf(v.x, scale.x, shift.x); v.y = fmaf(v.y, scale.y, shift.y);
        v.z = fmaf(v.z, scale.z, shift.z); v.w = fmaf(v.w, scale.w, shift.w);
        v.x = fmaxf(v.x, 0.01f * v.x); v.y = fmaxf(v.y, 0.01f * v.y);
        v.z = fmaxf(v.z, 0.01f * v.z); v.w = fmaxf(v.w, 0.01f * v.w);
        *reinterpret_cast<float4*>(p) = v;
    }
}

// ---------------------------------------------------------------------------
extern "C" void kernel_launch(void* const* d_in, const int* in_sizes, int n_in,
                              void* d_out, int out_size, void* d_ws, size_t ws_size,
                              hipStream_t stream)
{
    const float* x     = (const float*)d_in[0];
    const float* W_ih  = (const float*)d_in[1];
    const float* W_hh  = (const float*)d_in[2];
    const float* b_ih  = (const float*)d_in[3];
    const float* b_hh  = (const float*)d_in[4];
    const float* gamma = (const float*)d_in[5];
    const float* beta  = (const float*)d_in[6];

    float* y  = (float*)d_out;
    float* hn = y + (size_t)TB * TT * TH;
    float* cn = hn + TB * TH;

    float* ws_stats = (float*)d_ws;
    const size_t GX_BYTES = (size_t)TB * TT * TG * sizeof(float);
    // 4096 stats header + gx + 4 slack rows (producer prefetch reads past end)
    const bool use_ws = ws_size >= GX_BYTES + 4096 + 4 * TG * sizeof(float);

    bn_zero<<<1, 256, 0, stream>>>(ws_stats);

    if (use_ws) {
        float* gxbuf = (float*)((char*)d_ws + 4096);
        gx_precompute<<<2048, 256, 0, stream>>>(x, W_ih, b_ih, b_hh, gxbuf);
        lstm_scan_mfma5<<<TB, 320, 0, stream>>>(W_hh, gxbuf, y, hn, cn);
    } else {
        lstm_scan_fused<<<TB, 512, 0, stream>>>(x, W_ih, W_hh, b_ih, b_hh,
                                                y, hn, cn);
    }

    bn_stats<<<512, 256, 0, stream>>>(y, ws_stats);
    bn_apply<<<2048, 256, 0, stream>>>(y, ws_stats, gamma, beta);
}